// Round 19
// baseline (201.606 us; speedup 1.0000x reference)
//
#include <hip/hip_runtime.h>
#include <hip/hip_bf16.h>

typedef __attribute__((ext_vector_type(8))) short bf16x8;
typedef __attribute__((ext_vector_type(4))) float f32x4;

#define LOG2E 1.4426950408889634f

__device__ __forceinline__ unsigned short f2b(float f) {
  union { float f; unsigned u; } v; v.f = f;
  unsigned r = v.u + 0x7fffu + ((v.u >> 16) & 1u);
  return (unsigned short)(r >> 16);
}

// packed RNE f32x2 -> bf16x2 (v_cvt_pk_bf16_f32); identical rounding to f2b
__device__ __forceinline__ unsigned pack2(float a, float b) {
  __hip_bfloat162 h = __float22bfloat162_rn(make_float2(a, b));
  union { __hip_bfloat162 h; unsigned u; } v;
  v.h = h;
  return v.u;
}

// ---------------- cast X (fp32 -> bf16), 4 elems/thread ----------------
__global__ void cast_x_kernel(const float* __restrict__ X, unsigned short* __restrict__ Xb, int n4) {
  int i = blockIdx.x * blockDim.x + threadIdx.x;
  if (i < n4) {
    float4 v = reinterpret_cast<const float4*>(X)[i];
    ushort4 o = make_ushort4(f2b(v.x), f2b(v.y), f2b(v.z), f2b(v.w));
    reinterpret_cast<ushort4*>(Xb)[i] = o;
  }
}

// ------------- transpose+cast W [K][N] fp32 -> Wt [N][K] bf16 -------------
__global__ void transpose_cast_kernel(const float* __restrict__ W, unsigned short* __restrict__ Wt,
                                      int K, int N) {
  int lane = threadIdx.x & 63;
  int wave = threadIdx.x >> 6;
  int n = blockIdx.x * 64 + lane;
  int k0 = blockIdx.y * 32 + wave * 8;
  bf16x8 v;
#pragma unroll
  for (int j = 0; j < 8; ++j) v[j] = (short)f2b(W[(size_t)(k0 + j) * N + n]);
  *reinterpret_cast<bf16x8*>(&Wt[(size_t)n * K + k0]) = v;
}

// ---------------- GEMM C = A[M,K] * Bt[N,K]^T, bf16 in, fp32 accum --------
__device__ __forceinline__ void stage_tile(const unsigned short* __restrict__ A,
                                           const unsigned short* __restrict__ Bt,
                                           int m0, int n0, int kk, int K,
                                           unsigned short* As, unsigned short* Bs, int tid) {
  int wave = tid >> 6;
  int row = tid >> 2;
  int chunk = tid & 3;
  typedef __attribute__((address_space(3))) unsigned int lds_u32;
  typedef const __attribute__((address_space(1))) unsigned int glb_u32;
  const unsigned short* ga0 = A + (size_t)(m0 + row) * K + kk + chunk * 8;
  const unsigned short* ga1 = A + (size_t)(m0 + 64 + row) * K + kk + chunk * 8;
  const unsigned short* gb0 = Bt + (size_t)(n0 + row) * K + kk + chunk * 8;
  const unsigned short* gb1 = Bt + (size_t)(n0 + 64 + row) * K + kk + chunk * 8;
  __builtin_amdgcn_global_load_lds((glb_u32*)ga0, (lds_u32*)(As + wave * 512), 16, 0, 0);
  __builtin_amdgcn_global_load_lds((glb_u32*)ga1, (lds_u32*)(As + 2048 + wave * 512), 16, 0, 0);
  __builtin_amdgcn_global_load_lds((glb_u32*)gb0, (lds_u32*)(Bs + wave * 512), 16, 0, 0);
  __builtin_amdgcn_global_load_lds((glb_u32*)gb1, (lds_u32*)(Bs + 2048 + wave * 512), 16, 0, 0);
}

template <int MODE>
__launch_bounds__(256, 2)
__global__ void gemm_bt_kernel(const unsigned short* __restrict__ A,
                               const unsigned short* __restrict__ Bt,
                               void* __restrict__ Cout,
                               unsigned short* __restrict__ Vt,
                               int M, int N, int K) {
  __shared__ __align__(16) unsigned short As[2][128 * 32];
  __shared__ __align__(16) unsigned short Bs[2][128 * 32];
  const int tid = threadIdx.x;
  const int lane = tid & 63;
  const int wave = tid >> 6;
  const int wr = wave >> 1, wc = wave & 1;
  const int m0 = blockIdx.y * 128;
  const int n0 = blockIdx.x * 128;
  const int lr = lane & 15;
  const int lk = (lane >> 4) * 8;

  f32x4 zero = {0.f, 0.f, 0.f, 0.f};
  f32x4 acc[4][4];
#pragma unroll
  for (int i = 0; i < 4; ++i)
#pragma unroll
    for (int j = 0; j < 4; ++j) acc[i][j] = zero;

  const int KT = K >> 5;
  stage_tile(A, Bt, m0, n0, 0, K, As[0], Bs[0], tid);
  int buf = 0;
  for (int kt = 0; kt < KT; ++kt) {
    __syncthreads();
    if (kt + 1 < KT) stage_tile(A, Bt, m0, n0, (kt + 1) << 5, K, As[buf ^ 1], Bs[buf ^ 1], tid);
    bf16x8 af[4], bfr[4];
#pragma unroll
    for (int mf = 0; mf < 4; ++mf)
      af[mf] = *reinterpret_cast<const bf16x8*>(&As[buf][(wr * 64 + mf * 16 + lr) * 32 + lk]);
#pragma unroll
    for (int nf = 0; nf < 4; ++nf)
      bfr[nf] = *reinterpret_cast<const bf16x8*>(&Bs[buf][(wc * 64 + nf * 16 + lr) * 32 + lk]);
#pragma unroll
    for (int mf = 0; mf < 4; ++mf)
#pragma unroll
      for (int nf = 0; nf < 4; ++nf)
        acc[mf][nf] = __builtin_amdgcn_mfma_f32_16x16x32_bf16(af[mf], bfr[nf], acc[mf][nf], 0, 0, 0);
    buf ^= 1;
  }

  const int lj = (lane >> 4) * 4;
  if (MODE == 1) {
    float* C = (float*)Cout;
#pragma unroll
    for (int mf = 0; mf < 4; ++mf)
#pragma unroll
      for (int nf = 0; nf < 4; ++nf) {
        int n = n0 + wc * 64 + nf * 16 + lr;
#pragma unroll
        for (int j = 0; j < 4; ++j) {
          int m = m0 + wr * 64 + mf * 16 + lj + j;
          C[(size_t)m * N + n] = acc[mf][nf][j];
        }
      }
  } else {
    unsigned short* QK = (unsigned short*)Cout;
    if (n0 < 2048) {
#pragma unroll
      for (int mf = 0; mf < 4; ++mf)
#pragma unroll
        for (int nf = 0; nf < 4; ++nf) {
          int n = n0 + wc * 64 + nf * 16 + lr;
          float scale = (n < 1024) ? 0.125f : 1.0f;
#pragma unroll
          for (int j = 0; j < 4; ++j) {
            int m = m0 + wr * 64 + mf * 16 + lj + j;
            QK[(size_t)m * 2048 + n] = f2b(acc[mf][nf][j] * scale);
          }
        }
    } else {
      // V -> Vt[bh][d][t] (natural token order; j spans consecutive t)
#pragma unroll
      for (int mf = 0; mf < 4; ++mf)
#pragma unroll
        for (int nf = 0; nf < 4; ++nf) {
          int n = n0 - 2048 + wc * 64 + nf * 16 + lr;
          int d = n & 63, h = n >> 6;
          int mbase = m0 + wr * 64 + mf * 16 + lj;
          int bb = mbase >> 11, t = mbase & 2047;
          ushort4 v = make_ushort4(f2b(acc[mf][nf][0]), f2b(acc[mf][nf][1]),
                                   f2b(acc[mf][nf][2]), f2b(acc[mf][nf][3]));
          *reinterpret_cast<ushort4*>(&Vt[(((size_t)bb * 16 + h) * 64 + d) * 2048 + t]) = v;
        }
    }
  }
}

// ---------------- flash attention v18: split-strip, 2 chains, 4096 waves ---
// Model (R12-R18): concurrency = chains/SIMD never rose above 4 all session.
// Now: 4096 single-wave blocks (4 waves/SIMD, 2x R16) x 2 interleaved chains
// per wave = 8 chains/SIMD. Each wave owns ONE 16-row strip, split K-wise
// into equal halves (front kt=i, back kt=h+i), run as the R16 two-chain
// loop body (frozen P-path: PWRITE/PFENCE/PREAD). Front+back merged
// in-register via LSE (R18-validated). Rider: psum row-reduce deferred out
// of the loop (lsum per-lane; mnew is row-wide so fsc is row-uniform) ->
// 2 fewer serial ds_bpermute per tile.
#define PFENCE() asm volatile("s_waitcnt lgkmcnt(0)" ::: "memory")

#define KLOAD(KF, TK)                                                                             \
  {                                                                                               \
    const unsigned short* kp = Kbase + (size_t)((TK) << 6) * 2048;                                \
    _Pragma("unroll")                                                                             \
    for (int nf = 0; nf < 4; ++nf) {                                                              \
      const unsigned short* kq = kp + (size_t)(nf * 16) * 2048;                                   \
      KF[nf][0] = *reinterpret_cast<const bf16x8*>(kq);                                           \
      KF[nf][1] = *reinterpret_cast<const bf16x8*>(kq + 32);                                      \
    }                                                                                             \
  }

#define VLOADX(VF, TK)                                                                            \
  {                                                                                               \
    const unsigned short* vp0 = Vbase + ((TK) << 6);                                              \
    _Pragma("unroll")                                                                             \
    for (int mf = 0; mf < 4; ++mf) {                                                              \
      const unsigned short* vp = vp0 + (size_t)(mf * 16) * 2048;                                  \
      VF[mf][0] = *reinterpret_cast<const bf16x8*>(vp);                                           \
      VF[mf][1] = *reinterpret_cast<const bf16x8*>(vp + 32);                                      \
    }                                                                                             \
  }

#define QKC(ST, QF, KF)                                                                           \
  {                                                                                               \
    __builtin_amdgcn_s_setprio(1);                                                                \
    _Pragma("unroll")                                                                             \
    for (int nf = 0; nf < 4; ++nf) {                                                              \
      ST[nf] = __builtin_amdgcn_mfma_f32_16x16x32_bf16(KF[nf][0], QF[0], zero, 0, 0, 0);          \
      ST[nf] = __builtin_amdgcn_mfma_f32_16x16x32_bf16(KF[nf][1], QF[1], ST[nf], 0, 0, 0);        \
    }                                                                                             \
    __builtin_amdgcn_s_setprio(0);                                                                \
  }

#define MASKST(ST, NFD)                                                                           \
  {                                                                                               \
    _Pragma("unroll")                                                                             \
    for (int nf = 0; nf < 4; ++nf)                                                                \
      _Pragma("unroll")                                                                           \
      for (int j = 0; j < 4; ++j) {                                                               \
        bool kill = (nf > (NFD)) || ((nf == (NFD)) && (4 * lhi + j > lr));                        \
        ST[nf][j] = kill ? -1e30f : ST[nf][j];                                                    \
      }                                                                                           \
  }

// softmax with DEFERRED row-sum: lsum stays per-lane (mnew row-wide -> fsc
// row-uniform, so per-lane partials remain consistent); reduced at epilogue.
#define SMP(ST, MROW, LSUM, ACCO, WOUT)                                                           \
  {                                                                                               \
    float pmax = -1e30f;                                                                          \
    _Pragma("unroll")                                                                             \
    for (int nf = 0; nf < 4; ++nf)                                                                \
      _Pragma("unroll")                                                                           \
      for (int j = 0; j < 4; ++j) pmax = fmaxf(pmax, ST[nf][j]);                                  \
    pmax = fmaxf(pmax, __shfl_xor(pmax, 16));                                                     \
    pmax = fmaxf(pmax, __shfl_xor(pmax, 32));                                                     \
    const float mnew = fmaxf(MROW, pmax);                                                         \
    const float fsc = exp2f((MROW - mnew) * LOG2E);                                               \
    float psum = 0.f;                                                                             \
    _Pragma("unroll")                                                                             \
    for (int nf = 0; nf < 4; ++nf)                                                                \
      _Pragma("unroll")                                                                           \
      for (int h2 = 0; h2 < 2; ++h2) {                                                            \
        float p0 = exp2f((ST[nf][2 * h2] - mnew) * LOG2E);                                        \
        float p1 = exp2f((ST[nf][2 * h2 + 1] - mnew) * LOG2E);                                    \
        psum += p0 + p1;                                                                          \
        WOUT[nf * 2 + h2] = pack2(p0, p1);                                                        \
      }                                                                                           \
    LSUM = LSUM * fsc + psum; /* per-lane partial */                                              \
    MROW = mnew;                                                                                  \
    _Pragma("unroll")                                                                             \
    for (int mf = 0; mf < 4; ++mf)                                                                \
      _Pragma("unroll")                                                                           \
      for (int j = 0; j < 4; ++j) ACCO[mf][j] *= fsc;                                             \
  }

#define PWRITE(PW, WIN)                                                                           \
  {                                                                                               \
    uint4 w0 = make_uint4(WIN[0], WIN[1], WIN[2], WIN[3]);                                        \
    uint4 w1 = make_uint4(WIN[4], WIN[5], WIN[6], WIN[7]);                                        \
    *reinterpret_cast<uint4*>(&PW[lr][8 * lhi]) = w0;                                             \
    *reinterpret_cast<uint4*>(&PW[lr][8 * lhi + 4]) = w1;                                         \
  }

#define PREAD(PW, PB)                                                                             \
  {                                                                                               \
    _Pragma("unroll")                                                                             \
    for (int kd = 0; kd < 2; ++kd) {                                                              \
      const int nfk = 2 * kd + (lhi >> 1);                                                        \
      const int c = 2 * (nfk & 1) + 4 * (nfk >> 1);                                               \
      const int s0 = 8 * ((2 * lhi) & 3) + c;                                                     \
      const int s1 = 8 * ((2 * lhi + 1) & 3) + c;                                                 \
      union { bf16x8 v; unsigned int u[4]; } pu;                                                  \
      uint2 ra = *reinterpret_cast<const uint2*>(&PW[lr][s0]);                                    \
      uint2 rb = *reinterpret_cast<const uint2*>(&PW[lr][s1]);                                    \
      pu.u[0] = ra.x; pu.u[1] = ra.y; pu.u[2] = rb.x; pu.u[3] = rb.y;                             \
      PB[kd] = pu.v;                                                                              \
    }                                                                                             \
  }

#define PVC(ACCO, VF, PB)                                                                         \
  {                                                                                               \
    __builtin_amdgcn_s_setprio(1);                                                                \
    _Pragma("unroll")                                                                             \
    for (int mf = 0; mf < 4; ++mf) {                                                              \
      ACCO[mf] = __builtin_amdgcn_mfma_f32_16x16x32_bf16(VF[mf][0], PB[0], ACCO[mf], 0, 0, 0);    \
      ACCO[mf] = __builtin_amdgcn_mfma_f32_16x16x32_bf16(VF[mf][1], PB[1], ACCO[mf], 0, 0, 0);    \
    }                                                                                             \
    __builtin_amdgcn_s_setprio(0);                                                                \
  }

__launch_bounds__(64)
__global__ void attn_kernel(const unsigned short* __restrict__ QK,
                            const unsigned short* __restrict__ Vt,
                            unsigned short* __restrict__ O) {
  __shared__ unsigned int Pw[2][2][16][36];  // [pingpong][chain], frozen inner layout
  const int T = 2048;
  const int lane = threadIdx.x;  // one wave per block
  const int lr = lane & 15;
  const int lhi = lane >> 4;
  const int bh = blockIdx.x & 31;
  const int qs = 127 - (blockIdx.x >> 5);  // one strip per block; longest first
  const int b = bh >> 4, h0 = bh & 15;
  const int q0 = qs * 16;
  const int n = (qs >> 2) + 1;      // tile count, 1..32
  const int hsp = (n + 1) >> 1;     // split point
  const int cF = hsp, cB = n - hsp; // chain lengths (cF >= cB, both <= 16)
  const int nfd = qs & 3;

  const f32x4 zero = {0.f, 0.f, 0.f, 0.f};

  const unsigned short* Qp = QK + ((size_t)(b * T + q0 + lr)) * 2048 + h0 * 64 + lhi * 8;
  bf16x8 qf[2] = {*reinterpret_cast<const bf16x8*>(Qp),
                  *reinterpret_cast<const bf16x8*>(Qp + 32)};

  const unsigned short* Kbase = QK + ((size_t)(b * T + lr)) * 2048 + 1024 + h0 * 64 + lhi * 8;
  const unsigned short* Vbase = Vt + ((size_t)(bh * 64 + lr)) * 2048 + lhi * 8;

  bf16x8 kfF[4][2], kfB[4][2];
  KLOAD(kfF, 0);
  if (cB) KLOAD(kfB, hsp);

  f32x4 accF[4] = {zero, zero, zero, zero};
  f32x4 accB[4] = {zero, zero, zero, zero};
  float mF = -1e30f, lF = 0.f;
  float mB = -1e30f, lB = 0.f;

  for (int i = 0; i < cF; ++i) {
    const int pp = i & 1;
    const bool dB = i < cB;
    bf16x8 vfF[4][2], vfB[4][2];
    VLOADX(vfF, i);
    if (dB) VLOADX(vfB, hsp + i);

    f32x4 stF[4], stB[4];
    QKC(stF, qf, kfF);
    if (dB) QKC(stB, qf, kfB);
    {
      int tk = i + 1;
      if (tk > 31) tk = 31;
      KLOAD(kfF, tk);
    }
    if (dB) {
      int tk = hsp + i + 1;
      if (tk > 31) tk = 31;
      KLOAD(kfB, tk);
    }
    if (cB == 0 && i == cF - 1) MASKST(stF, nfd);  // diagonal in front only if back empty
    if (dB && i == cB - 1) MASKST(stB, nfd);       // otherwise diagonal is back's last

    unsigned WF[8], WB[8];
    SMP(stF, mF, lF, accF, WF);
    if (dB) SMP(stB, mB, lB, accB, WB);

    PWRITE(Pw[pp][0], WF);
    if (dB) PWRITE(Pw[pp][1], WB);
    PFENCE();  // compiler memory fence + lgkmcnt(0); validated R15/16
    bf16x8 pbF[2], pbB[2];
    PREAD(Pw[pp][0], pbF);
    if (dB) PREAD(Pw[pp][1], pbB);

    PVC(accF, vfF, pbF);
    if (dB) PVC(accB, vfB, pbB);
  }

  // deferred row-sum reduction (once per strip-half instead of per tile)
  lF += __shfl_xor(lF, 16);
  lF += __shfl_xor(lF, 32);
  lB += __shfl_xor(lB, 16);
  lB += __shfl_xor(lB, 32);

  // merge front + back (in-register LSE combine; back empty -> xb = 0)
  {
    const float m = fmaxf(mF, mB);
    const float xa = exp2f((mF - m) * LOG2E);
    const float xb = exp2f((mB - m) * LOG2E);
    const float inv = 1.0f / (lF * xa + lB * xb);
    unsigned short* Op = O + ((size_t)(b * T + q0 + lr)) * 1024 + h0 * 64 + 4 * lhi;
#pragma unroll
    for (int mf = 0; mf < 4; ++mf) {
      float o0 = (accF[mf][0] * xa + accB[mf][0] * xb) * inv;
      float o1 = (accF[mf][1] * xa + accB[mf][1] * xb) * inv;
      float o2 = (accF[mf][2] * xa + accB[mf][2] * xb) * inv;
      float o3 = (accF[mf][3] * xa + accB[mf][3] * xb) * inv;
      uint2 o = make_uint2(pack2(o0, o1), pack2(o2, o3));
      *reinterpret_cast<uint2*>(Op + 16 * mf) = o;
    }
  }
}

extern "C" void kernel_launch(void* const* d_in, const int* in_sizes, int n_in,
                              void* d_out, int out_size, void* d_ws, size_t ws_size,
                              hipStream_t stream) {
  const float* X = (const float*)d_in[0];
  const float* Wqkv = (const float*)d_in[1];
  const float* Wproj = (const float*)d_in[2];
  float* out = (float*)d_out;

  char* ws = (char*)d_ws;
  unsigned short* Xb     = (unsigned short*)(ws);
  unsigned short* WqkvT  = (unsigned short*)(ws + 8388608);
  unsigned short* WprojT = (unsigned short*)(ws + 14680064);
  unsigned short* QKb    = (unsigned short*)(ws + 16777216);
  unsigned short* Vt     = (unsigned short*)(ws + 33554432);
  unsigned short* Ob     = (unsigned short*)(ws + 41943040);

  cast_x_kernel<<<4096, 256, 0, stream>>>(X, Xb, 4194304 / 4);
  transpose_cast_kernel<<<dim3(48, 32), 256, 0, stream>>>(Wqkv, WqkvT, 1024, 3072);
  transpose_cast_kernel<<<dim3(16, 32), 256, 0, stream>>>(Wproj, WprojT, 1024, 1024);
  gemm_bt_kernel<0><<<dim3(24, 32), 256, 0, stream>>>(Xb, WqkvT, QKb, Vt, 4096, 3072, 1024);
  attn_kernel<<<4096, 64, 0, stream>>>(QKb, Vt, Ob);
  gemm_bt_kernel<1><<<dim3(8, 32), 256, 0, stream>>>(Ob, WprojT, out, nullptr, 4096, 1024, 1024);
}

// Round 20
// 151.429 us; speedup vs baseline: 1.3314x; 1.3314x over previous
//
#include <hip/hip_runtime.h>
#include <hip/hip_bf16.h>

typedef __attribute__((ext_vector_type(8))) short bf16x8;
typedef __attribute__((ext_vector_type(4))) float f32x4;

#define LOG2E 1.4426950408889634f

__device__ __forceinline__ unsigned short f2b(float f) {
  union { float f; unsigned u; } v; v.f = f;
  unsigned r = v.u + 0x7fffu + ((v.u >> 16) & 1u);
  return (unsigned short)(r >> 16);
}

// packed RNE f32x2 -> bf16x2 (v_cvt_pk_bf16_f32); identical rounding to f2b
__device__ __forceinline__ unsigned pack2(float a, float b) {
  __hip_bfloat162 h = __float22bfloat162_rn(make_float2(a, b));
  union { __hip_bfloat162 h; unsigned u; } v;
  v.h = h;
  return v.u;
}

// ---------------- cast X (fp32 -> bf16), 4 elems/thread ----------------
__global__ void cast_x_kernel(const float* __restrict__ X, unsigned short* __restrict__ Xb, int n4) {
  int i = blockIdx.x * blockDim.x + threadIdx.x;
  if (i < n4) {
    float4 v = reinterpret_cast<const float4*>(X)[i];
    ushort4 o = make_ushort4(f2b(v.x), f2b(v.y), f2b(v.z), f2b(v.w));
    reinterpret_cast<ushort4*>(Xb)[i] = o;
  }
}

// ------------- transpose+cast W [K][N] fp32 -> Wt [N][K] bf16 -------------
__global__ void transpose_cast_kernel(const float* __restrict__ W, unsigned short* __restrict__ Wt,
                                      int K, int N) {
  int lane = threadIdx.x & 63;
  int wave = threadIdx.x >> 6;
  int n = blockIdx.x * 64 + lane;
  int k0 = blockIdx.y * 32 + wave * 8;
  bf16x8 v;
#pragma unroll
  for (int j = 0; j < 8; ++j) v[j] = (short)f2b(W[(size_t)(k0 + j) * N + n]);
  *reinterpret_cast<bf16x8*>(&Wt[(size_t)n * K + k0]) = v;
}

// ---------------- GEMM C = A[M,K] * Bt[N,K]^T, bf16 in, fp32 accum --------
__device__ __forceinline__ void stage_tile(const unsigned short* __restrict__ A,
                                           const unsigned short* __restrict__ Bt,
                                           int m0, int n0, int kk, int K,
                                           unsigned short* As, unsigned short* Bs, int tid) {
  int wave = tid >> 6;
  int row = tid >> 2;
  int chunk = tid & 3;
  typedef __attribute__((address_space(3))) unsigned int lds_u32;
  typedef const __attribute__((address_space(1))) unsigned int glb_u32;
  const unsigned short* ga0 = A + (size_t)(m0 + row) * K + kk + chunk * 8;
  const unsigned short* ga1 = A + (size_t)(m0 + 64 + row) * K + kk + chunk * 8;
  const unsigned short* gb0 = Bt + (size_t)(n0 + row) * K + kk + chunk * 8;
  const unsigned short* gb1 = Bt + (size_t)(n0 + 64 + row) * K + kk + chunk * 8;
  __builtin_amdgcn_global_load_lds((glb_u32*)ga0, (lds_u32*)(As + wave * 512), 16, 0, 0);
  __builtin_amdgcn_global_load_lds((glb_u32*)ga1, (lds_u32*)(As + 2048 + wave * 512), 16, 0, 0);
  __builtin_amdgcn_global_load_lds((glb_u32*)gb0, (lds_u32*)(Bs + wave * 512), 16, 0, 0);
  __builtin_amdgcn_global_load_lds((glb_u32*)gb1, (lds_u32*)(Bs + 2048 + wave * 512), 16, 0, 0);
}

template <int MODE>
__launch_bounds__(256, 2)
__global__ void gemm_bt_kernel(const unsigned short* __restrict__ A,
                               const unsigned short* __restrict__ Bt,
                               void* __restrict__ Cout,
                               unsigned short* __restrict__ Vt,
                               int M, int N, int K) {
  __shared__ __align__(16) unsigned short As[2][128 * 32];
  __shared__ __align__(16) unsigned short Bs[2][128 * 32];
  const int tid = threadIdx.x;
  const int lane = tid & 63;
  const int wave = tid >> 6;
  const int wr = wave >> 1, wc = wave & 1;
  const int m0 = blockIdx.y * 128;
  const int n0 = blockIdx.x * 128;
  const int lr = lane & 15;
  const int lk = (lane >> 4) * 8;

  f32x4 zero = {0.f, 0.f, 0.f, 0.f};
  f32x4 acc[4][4];
#pragma unroll
  for (int i = 0; i < 4; ++i)
#pragma unroll
    for (int j = 0; j < 4; ++j) acc[i][j] = zero;

  const int KT = K >> 5;
  stage_tile(A, Bt, m0, n0, 0, K, As[0], Bs[0], tid);
  int buf = 0;
  for (int kt = 0; kt < KT; ++kt) {
    __syncthreads();
    if (kt + 1 < KT) stage_tile(A, Bt, m0, n0, (kt + 1) << 5, K, As[buf ^ 1], Bs[buf ^ 1], tid);
    bf16x8 af[4], bfr[4];
#pragma unroll
    for (int mf = 0; mf < 4; ++mf)
      af[mf] = *reinterpret_cast<const bf16x8*>(&As[buf][(wr * 64 + mf * 16 + lr) * 32 + lk]);
#pragma unroll
    for (int nf = 0; nf < 4; ++nf)
      bfr[nf] = *reinterpret_cast<const bf16x8*>(&Bs[buf][(wc * 64 + nf * 16 + lr) * 32 + lk]);
#pragma unroll
    for (int mf = 0; mf < 4; ++mf)
#pragma unroll
      for (int nf = 0; nf < 4; ++nf)
        acc[mf][nf] = __builtin_amdgcn_mfma_f32_16x16x32_bf16(af[mf], bfr[nf], acc[mf][nf], 0, 0, 0);
    buf ^= 1;
  }

  const int lj = (lane >> 4) * 4;
  if (MODE == 1) {
    float* C = (float*)Cout;
#pragma unroll
    for (int mf = 0; mf < 4; ++mf)
#pragma unroll
      for (int nf = 0; nf < 4; ++nf) {
        int n = n0 + wc * 64 + nf * 16 + lr;
#pragma unroll
        for (int j = 0; j < 4; ++j) {
          int m = m0 + wr * 64 + mf * 16 + lj + j;
          C[(size_t)m * N + n] = acc[mf][nf][j];
        }
      }
  } else {
    unsigned short* QK = (unsigned short*)Cout;
    if (n0 < 2048) {
#pragma unroll
      for (int mf = 0; mf < 4; ++mf)
#pragma unroll
        for (int nf = 0; nf < 4; ++nf) {
          int n = n0 + wc * 64 + nf * 16 + lr;
          float scale = (n < 1024) ? 0.125f : 1.0f;
#pragma unroll
          for (int j = 0; j < 4; ++j) {
            int m = m0 + wr * 64 + mf * 16 + lj + j;
            QK[(size_t)m * 2048 + n] = f2b(acc[mf][nf][j] * scale);
          }
        }
    } else {
      // V -> Vt[bh][d][t] (natural token order; j spans consecutive t)
#pragma unroll
      for (int mf = 0; mf < 4; ++mf)
#pragma unroll
        for (int nf = 0; nf < 4; ++nf) {
          int n = n0 - 2048 + wc * 64 + nf * 16 + lr;
          int d = n & 63, h = n >> 6;
          int mbase = m0 + wr * 64 + mf * 16 + lj;
          int bb = mbase >> 11, t = mbase & 2047;
          ushort4 v = make_ushort4(f2b(acc[mf][nf][0]), f2b(acc[mf][nf][1]),
                                   f2b(acc[mf][nf][2]), f2b(acc[mf][nf][3]));
          *reinterpret_cast<ushort4*>(&Vt[(((size_t)bb * 16 + h) * 64 + d) * 2048 + t]) = v;
        }
    }
  }
}

// ---------------- flash attention v19: EQUAL-length strip pairs ------------
// Model fit (R12->R13->R16->R19): attn time tracks TOTAL LOOP ITERATIONS;
// extra chains within an iteration are nearly free, and occupancy never
// moves. R16 paired longest-with-shortest (127-pid, pid): loop runs nA in
// [17,32] iters and the tail is single-chain. Now pair strips of EQUAL
// length (qs = 2j, 2j+1 share n=(j>>1)+1): both chains active in EVERY
// iteration, total iterations 50K -> 33.8K (-32%), same shared K/V loads.
// Loop body / SMP / frozen P-path (PWRITE/PFENCE/PREAD) = R16 verbatim,
// with actB guards removed (always true) and both masks at the final tile.
#define PFENCE() asm volatile("s_waitcnt lgkmcnt(0)" ::: "memory")

#define KLOAD(TK)                                                                                 \
  {                                                                                               \
    const unsigned short* kp = Kbase + (size_t)((TK) << 6) * 2048;                                \
    _Pragma("unroll")                                                                             \
    for (int nf = 0; nf < 4; ++nf) {                                                              \
      const unsigned short* kq = kp + (size_t)(nf * 16) * 2048;                                   \
      kf[nf][0] = *reinterpret_cast<const bf16x8*>(kq);                                           \
      kf[nf][1] = *reinterpret_cast<const bf16x8*>(kq + 32);                                      \
    }                                                                                             \
  }

#define VLOADX(VF, TK)                                                                            \
  {                                                                                               \
    const unsigned short* vp0 = Vbase + ((TK) << 6);                                              \
    _Pragma("unroll")                                                                             \
    for (int mf = 0; mf < 4; ++mf) {                                                              \
      const unsigned short* vp = vp0 + (size_t)(mf * 16) * 2048;                                  \
      VF[mf][0] = *reinterpret_cast<const bf16x8*>(vp);                                           \
      VF[mf][1] = *reinterpret_cast<const bf16x8*>(vp + 32);                                      \
    }                                                                                             \
  }

#define QKC(ST, QF)                                                                               \
  {                                                                                               \
    __builtin_amdgcn_s_setprio(1);                                                                \
    _Pragma("unroll")                                                                             \
    for (int nf = 0; nf < 4; ++nf) {                                                              \
      ST[nf] = __builtin_amdgcn_mfma_f32_16x16x32_bf16(kf[nf][0], QF[0], zero, 0, 0, 0);          \
      ST[nf] = __builtin_amdgcn_mfma_f32_16x16x32_bf16(kf[nf][1], QF[1], ST[nf], 0, 0, 0);        \
    }                                                                                             \
    __builtin_amdgcn_s_setprio(0);                                                                \
  }

#define MASKST(ST, NFD)                                                                           \
  {                                                                                               \
    _Pragma("unroll")                                                                             \
    for (int nf = 0; nf < 4; ++nf)                                                                \
      _Pragma("unroll")                                                                           \
      for (int j = 0; j < 4; ++j) {                                                               \
        bool kill = (nf > (NFD)) || ((nf == (NFD)) && (4 * lhi + j > lr));                        \
        ST[nf][j] = kill ? -1e30f : ST[nf][j];                                                    \
      }                                                                                           \
  }

#define SMP(ST, MROW, LSUM, ACCO, WOUT)                                                           \
  {                                                                                               \
    float pmax = -1e30f;                                                                          \
    _Pragma("unroll")                                                                             \
    for (int nf = 0; nf < 4; ++nf)                                                                \
      _Pragma("unroll")                                                                           \
      for (int j = 0; j < 4; ++j) pmax = fmaxf(pmax, ST[nf][j]);                                  \
    pmax = fmaxf(pmax, __shfl_xor(pmax, 16));                                                     \
    pmax = fmaxf(pmax, __shfl_xor(pmax, 32));                                                     \
    const float mnew = fmaxf(MROW, pmax);                                                         \
    const float fsc = exp2f((MROW - mnew) * LOG2E);                                               \
    float psum = 0.f;                                                                             \
    _Pragma("unroll")                                                                             \
    for (int nf = 0; nf < 4; ++nf)                                                                \
      _Pragma("unroll")                                                                           \
      for (int h2 = 0; h2 < 2; ++h2) {                                                            \
        float p0 = exp2f((ST[nf][2 * h2] - mnew) * LOG2E);                                        \
        float p1 = exp2f((ST[nf][2 * h2 + 1] - mnew) * LOG2E);                                    \
        psum += p0 + p1;                                                                          \
        WOUT[nf * 2 + h2] = pack2(p0, p1);                                                        \
      }                                                                                           \
    psum += __shfl_xor(psum, 16);                                                                 \
    psum += __shfl_xor(psum, 32);                                                                 \
    LSUM = LSUM * fsc + psum;                                                                     \
    MROW = mnew;                                                                                  \
    _Pragma("unroll")                                                                             \
    for (int mf = 0; mf < 4; ++mf)                                                                \
      _Pragma("unroll")                                                                           \
      for (int j = 0; j < 4; ++j) ACCO[mf][j] *= fsc;                                             \
  }

#define PWRITE(PW, WIN)                                                                           \
  {                                                                                               \
    uint4 w0 = make_uint4(WIN[0], WIN[1], WIN[2], WIN[3]);                                        \
    uint4 w1 = make_uint4(WIN[4], WIN[5], WIN[6], WIN[7]);                                        \
    *reinterpret_cast<uint4*>(&PW[lr][8 * lhi]) = w0;                                             \
    *reinterpret_cast<uint4*>(&PW[lr][8 * lhi + 4]) = w1;                                         \
  }

#define PREAD(PW, PB)                                                                             \
  {                                                                                               \
    _Pragma("unroll")                                                                             \
    for (int kd = 0; kd < 2; ++kd) {                                                              \
      const int nfk = 2 * kd + (lhi >> 1);                                                        \
      const int c = 2 * (nfk & 1) + 4 * (nfk >> 1);                                               \
      const int s0 = 8 * ((2 * lhi) & 3) + c;                                                     \
      const int s1 = 8 * ((2 * lhi + 1) & 3) + c;                                                 \
      union { bf16x8 v; unsigned int u[4]; } pu;                                                  \
      uint2 ra = *reinterpret_cast<const uint2*>(&PW[lr][s0]);                                    \
      uint2 rb = *reinterpret_cast<const uint2*>(&PW[lr][s1]);                                    \
      pu.u[0] = ra.x; pu.u[1] = ra.y; pu.u[2] = rb.x; pu.u[3] = rb.y;                             \
      PB[kd] = pu.v;                                                                              \
    }                                                                                             \
  }

#define PVC(ACCO, VF, PB)                                                                         \
  {                                                                                               \
    __builtin_amdgcn_s_setprio(1);                                                                \
    _Pragma("unroll")                                                                             \
    for (int mf = 0; mf < 4; ++mf) {                                                              \
      ACCO[mf] = __builtin_amdgcn_mfma_f32_16x16x32_bf16(VF[mf][0], PB[0], ACCO[mf], 0, 0, 0);    \
      ACCO[mf] = __builtin_amdgcn_mfma_f32_16x16x32_bf16(VF[mf][1], PB[1], ACCO[mf], 0, 0, 0);    \
    }                                                                                             \
    __builtin_amdgcn_s_setprio(0);                                                                \
  }

__launch_bounds__(64)
__global__ void attn_kernel(const unsigned short* __restrict__ QK,
                            const unsigned short* __restrict__ Vt,
                            unsigned short* __restrict__ O) {
  __shared__ unsigned int Pw[2][2][16][36];  // [strip][pingpong], frozen inner layout
  const int T = 2048;
  const int lane = threadIdx.x;  // one wave per block
  const int lr = lane & 15;
  const int lhi = lane >> 4;
  const int bh = blockIdx.x & 31;
  const int j = 63 - (blockIdx.x >> 5);  // pair index; longest pairs dispatch first
  const int b = bh >> 4, h = bh & 15;
  const int qsA = 2 * j + 1, qsB = 2 * j;  // EQUAL tile counts: n = (j>>1)+1
  const int q0A = qsA * 16, q0B = qsB * 16;
  const int ktmax = (qsB >> 2);  // == (qsA>>2); last (diagonal) 64-key tile
  const int nfdA = qsA & 3, nfdB = qsB & 3;

  const f32x4 zero = {0.f, 0.f, 0.f, 0.f};

  const unsigned short* QpA = QK + ((size_t)(b * T + q0A + lr)) * 2048 + h * 64 + lhi * 8;
  const unsigned short* QpB = QK + ((size_t)(b * T + q0B + lr)) * 2048 + h * 64 + lhi * 8;
  bf16x8 qfA[2] = {*reinterpret_cast<const bf16x8*>(QpA),
                   *reinterpret_cast<const bf16x8*>(QpA + 32)};
  bf16x8 qfB[2] = {*reinterpret_cast<const bf16x8*>(QpB),
                   *reinterpret_cast<const bf16x8*>(QpB + 32)};

  const unsigned short* Kbase = QK + ((size_t)(b * T + lr)) * 2048 + 1024 + h * 64 + lhi * 8;
  const unsigned short* Vbase = Vt + ((size_t)(bh * 64 + lr)) * 2048 + lhi * 8;

  bf16x8 kf[4][2];
  KLOAD(0);

  f32x4 accA[4] = {zero, zero, zero, zero};
  f32x4 accB[4] = {zero, zero, zero, zero};
  float mrowA = -1e30f, lsumA = 0.f, mrowB = -1e30f, lsumB = 0.f;

  for (int kt = 0; kt <= ktmax; ++kt) {
    const int pp = kt & 1;
    bf16x8 vf[4][2];  // shared by both strips (same (b,h), same kt)
    VLOADX(vf, kt);

    f32x4 stA[4], stB[4];
    QKC(stA, qfA);
    QKC(stB, qfB);
    {
      int tk = (kt + 1 > ktmax) ? ktmax : kt + 1;
      KLOAD(tk);
    }
    if (kt == ktmax) {
      MASKST(stA, nfdA);
      MASKST(stB, nfdB);
    }

    unsigned WA[8], WB[8];
    SMP(stA, mrowA, lsumA, accA, WA);
    SMP(stB, mrowB, lsumB, accB, WB);

    PWRITE(Pw[0][pp], WA);
    PWRITE(Pw[1][pp], WB);
    PFENCE();  // compiler memory fence + lgkmcnt(0); validated R15/16
    bf16x8 pbA[2], pbB[2];
    PREAD(Pw[0][pp], pbA);
    PREAD(Pw[1][pp], pbB);

    PVC(accA, vf, pbA);
    PVC(accB, vf, pbB);
  }

  {
    const float inv = 1.0f / lsumA;
    unsigned short* Op = O + ((size_t)(b * T + q0A + lr)) * 1024 + h * 64 + 4 * lhi;
#pragma unroll
    for (int mf = 0; mf < 4; ++mf) {
      uint2 o = make_uint2(pack2(accA[mf][0] * inv, accA[mf][1] * inv),
                           pack2(accA[mf][2] * inv, accA[mf][3] * inv));
      *reinterpret_cast<uint2*>(Op + 16 * mf) = o;
    }
  }
  {
    const float inv = 1.0f / lsumB;
    unsigned short* Op = O + ((size_t)(b * T + q0B + lr)) * 1024 + h * 64 + 4 * lhi;
#pragma unroll
    for (int mf = 0; mf < 4; ++mf) {
      uint2 o = make_uint2(pack2(accB[mf][0] * inv, accB[mf][1] * inv),
                           pack2(accB[mf][2] * inv, accB[mf][3] * inv));
      *reinterpret_cast<uint2*>(Op + 16 * mf) = o;
    }
  }
}

extern "C" void kernel_launch(void* const* d_in, const int* in_sizes, int n_in,
                              void* d_out, int out_size, void* d_ws, size_t ws_size,
                              hipStream_t stream) {
  const float* X = (const float*)d_in[0];
  const float* Wqkv = (const float*)d_in[1];
  const float* Wproj = (const float*)d_in[2];
  float* out = (float*)d_out;

  char* ws = (char*)d_ws;
  unsigned short* Xb     = (unsigned short*)(ws);
  unsigned short* WqkvT  = (unsigned short*)(ws + 8388608);
  unsigned short* WprojT = (unsigned short*)(ws + 14680064);
  unsigned short* QKb    = (unsigned short*)(ws + 16777216);
  unsigned short* Vt     = (unsigned short*)(ws + 33554432);
  unsigned short* Ob     = (unsigned short*)(ws + 41943040);

  cast_x_kernel<<<4096, 256, 0, stream>>>(X, Xb, 4194304 / 4);
  transpose_cast_kernel<<<dim3(48, 32), 256, 0, stream>>>(Wqkv, WqkvT, 1024, 3072);
  transpose_cast_kernel<<<dim3(16, 32), 256, 0, stream>>>(Wproj, WprojT, 1024, 1024);
  gemm_bt_kernel<0><<<dim3(24, 32), 256, 0, stream>>>(Xb, WqkvT, QKb, Vt, 4096, 3072, 1024);
  attn_kernel<<<2048, 64, 0, stream>>>(QKb, Vt, Ob);
  gemm_bt_kernel<1><<<dim3(8, 32), 256, 0, stream>>>(Ob, WprojT, out, nullptr, 4096, 1024, 1024);
}